// Round 4
// baseline (145.268 us; speedup 1.0000x reference)
//
#include <hip/hip_runtime.h>

#define NJ   17
#define FD   128
#define NC   128
#define NNZ  49
#define FR   2
#define RPB  (FR * NJ)    // 34 rows per tile

// d_ws layout
#define WS_WNB  65536                 // bf16 wnorm [NNZ][NC] after Wpack
#define WS_RP   (WS_WNB + NNZ*NC*2)   // int rp[NJ+1]

typedef __attribute__((ext_vector_type(8))) short bf16x8;   // 8 bf16
typedef __attribute__((ext_vector_type(4))) float f32x4;

__device__ __forceinline__ ushort f2bf(float f) {   // f32 -> bf16 RNE
  unsigned u = __float_as_uint(f);
  u = (u + 0x7fffu + ((u >> 16) & 1u)) >> 16;
  return (ushort)u;
}
__device__ __forceinline__ float bf2f(ushort s) {
  return __uint_as_float(((unsigned)s) << 16);
}

// ---------------------------------------------------------------------------
// Prep+pack merged (17 blocks x 256):
//  blocks 0..15: pack W f32 [2][128][128] -> bf16 B-frag layout
//                Wpack bf16 idx = n*128 + kb*8 + e <=> W[n>>7][kb*8+e][n&127]
//  block 16:     adjacency softmax -> bf16 wnorm[k][c] + rp[NJ+1]
// ---------------------------------------------------------------------------
__global__ void prep_pack_kernel(const float* __restrict__ W,
                                 const float* __restrict__ e,
                                 const int*   __restrict__ ii,
                                 bf16x8*      __restrict__ Wpack,
                                 ushort*      __restrict__ wnb,
                                 int*         __restrict__ rp_out) {
  const int tid = threadIdx.x;
  if (blockIdx.x < 16) {
    const int idx = blockIdx.x * 256 + tid;     // [0,4096)
    const int n = idx >> 4, kb = idx & 15;
    const float* Wp = W + (size_t)(n >> 7) * (FD * NC) + (n & 127);
    bf16x8 v;
#pragma unroll
    for (int q = 0; q < 8; ++q)
      v[q] = (short)f2bf(Wp[(size_t)(kb * 8 + q) * NC]);
    Wpack[idx] = v;
  } else {
    __shared__ int rp[NJ + 1];
    if (tid == 0) {
      int pos = 0;
      for (int j = 0; j <= NJ; ++j) {
        while (pos < NNZ && ii[pos] < j) ++pos;
        rp[j] = pos;
        rp_out[j] = pos;
      }
    }
    __syncthreads();
    if (tid < NC) {
      const int c = tid;
      for (int j = 0; j < NJ; ++j) {
        const int k0 = rp[j], k1 = rp[j + 1];
        float m = -1e30f;
        for (int k = k0; k < k1; ++k) m = fmaxf(m, e[c * NNZ + k]);
        float s = 0.f;
        for (int k = k0; k < k1; ++k) s += expf(e[c * NNZ + k] - m);
        const float inv = 1.f / s;
        for (int k = k0; k < k1; ++k)
          wnb[k * NC + c] = f2bf(expf(e[c * NNZ + k] - m) * inv);
      }
    }
  }
}

// ---------------------------------------------------------------------------
// Fused kernel: persistent-ish blocks, grid-stride over FR=2 tiles,
// reg-staged 1-deep prefetch, double-buffered x LDS.
// Per tile: [loads t+1 in flight] barrier -> MFMA -> barrier -> agg -> stage.
// ---------------------------------------------------------------------------
__global__ __launch_bounds__(256, 3) void fused_kernel(
    const float*  __restrict__ x,
    const bf16x8* __restrict__ Wpack,
    const ushort* __restrict__ wnb,
    const int*    __restrict__ rp,
    const int*    __restrict__ idxj,
    float*        __restrict__ out,
    int ntiles) {
  __shared__ __align__(16) short  xs[2][RPB * FD];   // bf16 x, swizzled (17.4 KB)
  __shared__ __align__(16) short  hsm[RPB * 256];    // bf16 h, swizzled (17.4 KB)
  __shared__ __align__(16) ushort wkb[NNZ * NC];     // bf16 wnorm (12.5 KB)
  __shared__ int rps[NJ + 1];
  __shared__ int jjs[NNZ];

  const int tid  = threadIdx.x;
  const int w    = tid >> 6;
  const int lane = tid & 63;
  const int l15  = lane & 15;
  const int l4   = lane >> 4;
  const int stride = gridDim.x;

  if (tid < NJ + 1) rps[tid] = rp[tid];
  if (tid >= 32 && tid < 32 + NNZ) jjs[tid - 32] = idxj[tid - 32];
#pragma unroll
  for (int i = 0; i < 7; ++i) {                    // 1568 ushort4 total
    const int idx = tid + i * 256;
    if (idx < NNZ * NC / 4)
      ((ushort4*)wkb)[idx] = ((const ushort4*)wnb)[idx];
  }

  // ---- persistent B fragments: wave w owns GEMM cols [64w, 64w+64) ----
  bf16x8 bfrag[4][4];
#pragma unroll
  for (int nt = 0; nt < 4; ++nt) {
    const int n = w * 64 + nt * 16 + l15;
#pragma unroll
    for (int ks = 0; ks < 4; ++ks)
      bfrag[nt][ks] = Wpack[n * 16 + ks * 4 + l4];
  }

  float4 pf0, pf1, pf2, pf3, pf4;

#define LOADX(T) do {                                                   \
    const float* xp_ = x + (size_t)(T) * (RPB * FD);                    \
    pf0 = *(const float4*)(xp_ + (size_t)tid * 4);                      \
    pf1 = *(const float4*)(xp_ + (size_t)(tid + 256) * 4);              \
    pf2 = *(const float4*)(xp_ + (size_t)(tid + 512) * 4);              \
    pf3 = *(const float4*)(xp_ + (size_t)(tid + 768) * 4);              \
    if (tid < 64) pf4 = *(const float4*)(xp_ + (size_t)(tid + 1024) * 4); \
  } while (0)

#define STW(XB, PF, IDX) do {                                           \
    const int row_ = (IDX) >> 5, seg_ = (IDX) & 31;                     \
    ushort4 b_;                                                         \
    b_.x = f2bf(PF.x); b_.y = f2bf(PF.y);                               \
    b_.z = f2bf(PF.z); b_.w = f2bf(PF.w);                               \
    *(ushort4*)((char*)(XB) + row_ * 256 + ((seg_ * 8) ^ ((row_ & 7) << 4))) = b_; \
  } while (0)

#define STAGE(B) do {                                                   \
    short* xb_ = xs[B];                                                 \
    STW(xb_, pf0, tid);                                                 \
    STW(xb_, pf1, tid + 256);                                           \
    STW(xb_, pf2, tid + 512);                                           \
    STW(xb_, pf3, tid + 768);                                           \
    if (tid < 64) STW(xb_, pf4, tid + 1024);                            \
  } while (0)

  int t = blockIdx.x;
  LOADX(t);
  STAGE(0);
  int buf = 0;

  const int m0tab[3] = {0, 16, 18};

  for (; t < ntiles; t += stride) {
    const int  tn   = t + stride;
    const bool more = (tn < ntiles);
    if (more) LOADX(tn);          // in flight across compute+agg

    __syncthreads();              // xs[buf] staged; hsm free (prev agg done)

    // ---- MFMA GEMM: 3 M-tiles {0,16,18}, overlap tile writes rows>=32 ----
    {
      const short* xb = xs[buf];
#pragma unroll
      for (int m = 0; m < 3; ++m) {
        const int arow = m0tab[m] + l15;
        const int sw = (arow & 7) << 4;
        bf16x8 af[4];
#pragma unroll
        for (int ks = 0; ks < 4; ++ks)
          af[ks] = *(const bf16x8*)((const char*)xb + arow * 256 +
                                    ((l4 * 16 + ks * 64) ^ sw));
#pragma unroll
        for (int nt = 0; nt < 4; ++nt) {
          f32x4 acc = (f32x4){0.f, 0.f, 0.f, 0.f};
#pragma unroll
          for (int ks = 0; ks < 4; ++ks)
            acc = __builtin_amdgcn_mfma_f32_16x16x32_bf16(af[ks], bfrag[nt][ks],
                                                          acc, 0, 0, 0);
          const int n = w * 64 + nt * 16 + l15;
#pragma unroll
          for (int q = 0; q < 4; ++q) {
            const int rr = m0tab[m] + l4 * 4 + q;
            if (m < 2 || rr >= 32)
              *(short*)((char*)hsm + rr * 512 + ((n * 2) ^ ((rr & 7) << 4))) =
                  (short)f2bf(acc[q]);
          }
        }
      }
    }

    __syncthreads();              // hsm ready

    // ---- aggregation: out[r,c] = sum_k wk[k,c] * h[nbr, diag?c:128+c] ----
    {
      const int c0 = (tid & 31) * 4;
      float* op = out + (size_t)t * (RPB * NC);
#pragma unroll
      for (int u = 0; u < 5; ++u) {
        const int r = (tid >> 5) + u * 8;
        if (r < RPB) {
          const int j  = (r >= NJ) ? r - NJ : r;
          const int fb = r - j;
          const int k0 = rps[j], k1 = rps[j + 1];
          float4 o = make_float4(0.f, 0.f, 0.f, 0.f);
          for (int k = k0; k < k1; ++k) {
            const int col = jjs[k];
            const ushort4 wk = *(const ushort4*)&wkb[k * NC + c0];
            const int hr = fb + col;
            const int nb = ((col == j ? 0 : 128) + c0) * 2;
            const ushort4 hv = *(const ushort4*)((const char*)hsm + hr * 512 +
                                                 (nb ^ ((hr & 7) << 4)));
            o.x += bf2f(wk.x) * bf2f(hv.x);
            o.y += bf2f(wk.y) * bf2f(hv.y);
            o.z += bf2f(wk.z) * bf2f(hv.z);
            o.w += bf2f(wk.w) * bf2f(hv.w);
          }
          *(float4*)(op + r * NC + c0) = o;
        }
      }
    }

    if (more) {                   // stage next tile (vmcnt wait inserted here)
      STAGE(buf ^ 1);
      buf ^= 1;
    }
  }
#undef LOADX
#undef STW
#undef STAGE
}

// ---------------------------------------------------------------------------
extern "C" void kernel_launch(void* const* d_in, const int* in_sizes, int n_in,
                              void* d_out, int out_size, void* d_ws, size_t ws_size,
                              hipStream_t stream) {
  const float* x  = (const float*)d_in[0];  // [B,T,J,F]
  const float* W  = (const float*)d_in[1];  // [2,F,C]
  const float* e  = (const float*)d_in[2];  // [C,NNZ]
  const int*   ii = (const int*)d_in[3];    // [NNZ]
  const int*   jj = (const int*)d_in[4];    // [NNZ]
  float* out = (float*)d_out;

  bf16x8* Wpack = (bf16x8*)d_ws;
  ushort* wnb   = (ushort*)((char*)d_ws + WS_WNB);
  int*    rpp   = (int*)((char*)d_ws + WS_RP);

  prep_pack_kernel<<<17, 256, 0, stream>>>((const float*)d_in[1], e, ii,
                                           Wpack, wnb, rpp);

  const int frames = in_sizes[0] / (NJ * FD);   // 15552
  const int ntiles = frames / FR;               // 7776
  fused_kernel<<<768, 256, 0, stream>>>(x, Wpack, wnb, rpp, jj, out, ntiles);
}

// Round 5
// 144.759 us; speedup vs baseline: 1.0035x; 1.0035x over previous
//
#include <hip/hip_runtime.h>

#define NJ   17
#define FD   128
#define NC   128
#define NNZ  49
#define FR   2
#define RPB  (FR * NJ)    // 34 rows per tile

// d_ws layout
#define WS_WNB  65536                 // bf16 wnorm [NNZ][NC] after Wpack
#define WS_RP   (WS_WNB + NNZ*NC*2)   // int rp[NJ+1]

typedef __attribute__((ext_vector_type(8))) short bf16x8;   // 8 bf16
typedef __attribute__((ext_vector_type(4))) float f32x4;

__device__ __forceinline__ ushort f2bf(float f) {   // f32 -> bf16 RNE
  unsigned u = __float_as_uint(f);
  u = (u + 0x7fffu + ((u >> 16) & 1u)) >> 16;
  return (ushort)u;
}
__device__ __forceinline__ float bf2f(ushort s) {
  return __uint_as_float(((unsigned)s) << 16);
}

// LDS-only barrier: drains ds ops (lgkm) but leaves global loads/stores
// (vmcnt) in flight across the barrier. __syncthreads() would emit
// s_waitcnt vmcnt(0) and kill the prefetch every tile.
#define BAR() do {                                          \
    asm volatile("s_waitcnt lgkmcnt(0)" ::: "memory");      \
    __builtin_amdgcn_s_barrier();                           \
    __builtin_amdgcn_sched_barrier(0);                      \
  } while (0)

// ---------------------------------------------------------------------------
// Prep+pack merged (17 blocks x 256):
//  blocks 0..15: pack W f32 [2][128][128] -> bf16 B-frag layout
//                Wpack bf16 idx = n*128 + kb*8 + e <=> W[n>>7][kb*8+e][n&127]
//  block 16:     adjacency softmax -> bf16 wnorm[k][c] + rp[NJ+1]
// ---------------------------------------------------------------------------
__global__ void prep_pack_kernel(const float* __restrict__ W,
                                 const float* __restrict__ e,
                                 const int*   __restrict__ ii,
                                 bf16x8*      __restrict__ Wpack,
                                 ushort*      __restrict__ wnb,
                                 int*         __restrict__ rp_out) {
  const int tid = threadIdx.x;
  if (blockIdx.x < 16) {
    const int idx = blockIdx.x * 256 + tid;     // [0,4096)
    const int n = idx >> 4, kb = idx & 15;
    const float* Wp = W + (size_t)(n >> 7) * (FD * NC) + (n & 127);
    bf16x8 v;
#pragma unroll
    for (int q = 0; q < 8; ++q)
      v[q] = (short)f2bf(Wp[(size_t)(kb * 8 + q) * NC]);
    Wpack[idx] = v;
  } else {
    __shared__ int rp[NJ + 1];
    if (tid == 0) {
      int pos = 0;
      for (int j = 0; j <= NJ; ++j) {
        while (pos < NNZ && ii[pos] < j) ++pos;
        rp[j] = pos;
        rp_out[j] = pos;
      }
    }
    __syncthreads();
    if (tid < NC) {
      const int c = tid;
      for (int j = 0; j < NJ; ++j) {
        const int k0 = rp[j], k1 = rp[j + 1];
        float m = -1e30f;
        for (int k = k0; k < k1; ++k) m = fmaxf(m, e[c * NNZ + k]);
        float s = 0.f;
        for (int k = k0; k < k1; ++k) s += expf(e[c * NNZ + k] - m);
        const float inv = 1.f / s;
        for (int k = k0; k < k1; ++k)
          wnb[k * NC + c] = f2bf(expf(e[c * NNZ + k] - m) * inv);
      }
    }
  }
}

// ---------------------------------------------------------------------------
// Fused kernel: grid-stride over FR=2 tiles, reg-staged 1-deep prefetch,
// double-buffered x LDS, lgkm-only barriers (prefetch stays in flight).
// ---------------------------------------------------------------------------
__global__ __launch_bounds__(256, 3) void fused_kernel(
    const float*  __restrict__ x,
    const bf16x8* __restrict__ Wpack,
    const ushort* __restrict__ wnb,
    const int*    __restrict__ rp,
    const int*    __restrict__ idxj,
    float*        __restrict__ out,
    int ntiles) {
  __shared__ __align__(16) short  xs[2][RPB * FD];   // bf16 x, swizzled (17.4 KB)
  __shared__ __align__(16) short  hsm[RPB * 256];    // bf16 h, swizzled (17.4 KB)
  __shared__ __align__(16) ushort wkb[NNZ * NC];     // bf16 wnorm (12.25 KB)
  __shared__ int rps[NJ + 1];
  __shared__ int jjs[NNZ];

  const int tid  = threadIdx.x;
  const int w    = tid >> 6;
  const int lane = tid & 63;
  const int l15  = lane & 15;
  const int l4   = lane >> 4;
  const int stride = gridDim.x;

  if (tid < NJ + 1) rps[tid] = rp[tid];
  if (tid >= 32 && tid < 32 + NNZ) jjs[tid - 32] = idxj[tid - 32];
#pragma unroll
  for (int i = 0; i < 7; ++i) {                    // 1568 ushort4 total
    const int idx = tid + i * 256;
    if (idx < NNZ * NC / 4)
      ((ushort4*)wkb)[idx] = ((const ushort4*)wnb)[idx];
  }

  // ---- persistent B fragments: wave w owns GEMM cols [64w, 64w+64) ----
  bf16x8 bfrag[4][4];
#pragma unroll
  for (int nt = 0; nt < 4; ++nt) {
    const int n = w * 64 + nt * 16 + l15;
#pragma unroll
    for (int ks = 0; ks < 4; ++ks)
      bfrag[nt][ks] = Wpack[n * 16 + ks * 4 + l4];
  }

  float4 pf0, pf1, pf2, pf3, pf4;

#define LOADX(T) do {                                                   \
    const float* xp_ = x + (size_t)(T) * (RPB * FD);                    \
    pf0 = *(const float4*)(xp_ + (size_t)tid * 4);                      \
    pf1 = *(const float4*)(xp_ + (size_t)(tid + 256) * 4);              \
    pf2 = *(const float4*)(xp_ + (size_t)(tid + 512) * 4);              \
    pf3 = *(const float4*)(xp_ + (size_t)(tid + 768) * 4);              \
    if (tid < 64) pf4 = *(const float4*)(xp_ + (size_t)(tid + 1024) * 4); \
  } while (0)

#define STW(XB, PF, IDX) do {                                           \
    const int row_ = (IDX) >> 5, seg_ = (IDX) & 31;                     \
    ushort4 b_;                                                         \
    b_.x = f2bf(PF.x); b_.y = f2bf(PF.y);                               \
    b_.z = f2bf(PF.z); b_.w = f2bf(PF.w);                               \
    *(ushort4*)((char*)(XB) + row_ * 256 + ((seg_ * 8) ^ ((row_ & 7) << 4))) = b_; \
  } while (0)

#define STAGE(B) do {                                                   \
    short* xb_ = xs[B];                                                 \
    STW(xb_, pf0, tid);                                                 \
    STW(xb_, pf1, tid + 256);                                           \
    STW(xb_, pf2, tid + 512);                                           \
    STW(xb_, pf3, tid + 768);                                           \
    if (tid < 64) STW(xb_, pf4, tid + 1024);                            \
  } while (0)

  int t = blockIdx.x;
  LOADX(t);
  STAGE(0);
  int buf = 0;

  const int m0tab[3] = {0, 16, 18};

  for (; t < ntiles; t += stride) {
    const int  tn   = t + stride;
    const bool more = (tn < ntiles);
    if (more) LOADX(tn);          // stays in flight across MFMA + agg

    BAR();                        // xs[buf] visible; hsm free (prev agg done)

    // ---- MFMA GEMM: 3 M-tiles {0,16,18}, overlap tile writes rows>=32 ----
    {
      const short* xb = xs[buf];
#pragma unroll
      for (int m = 0; m < 3; ++m) {
        const int arow = m0tab[m] + l15;
        const int sw = (arow & 7) << 4;
        bf16x8 af[4];
#pragma unroll
        for (int ks = 0; ks < 4; ++ks)
          af[ks] = *(const bf16x8*)((const char*)xb + arow * 256 +
                                    ((l4 * 16 + ks * 64) ^ sw));
#pragma unroll
        for (int nt = 0; nt < 4; ++nt) {
          f32x4 acc = (f32x4){0.f, 0.f, 0.f, 0.f};
#pragma unroll
          for (int ks = 0; ks < 4; ++ks)
            acc = __builtin_amdgcn_mfma_f32_16x16x32_bf16(af[ks], bfrag[nt][ks],
                                                          acc, 0, 0, 0);
          const int n = w * 64 + nt * 16 + l15;
#pragma unroll
          for (int q = 0; q < 4; ++q) {
            const int rr = m0tab[m] + l4 * 4 + q;
            if (m < 2 || rr >= 32)
              *(short*)((char*)hsm + rr * 512 + ((n * 2) ^ ((rr & 7) << 4))) =
                  (short)f2bf(acc[q]);
          }
        }
      }
    }

    BAR();                        // hsm visible

    // ---- aggregation: out[r,c] = sum_k wk[k,c] * h[nbr, diag?c:128+c] ----
    {
      const int c0 = (tid & 31) * 4;
      float* op = out + (size_t)t * (RPB * NC);
#pragma unroll
      for (int u = 0; u < 5; ++u) {
        const int r = (tid >> 5) + u * 8;
        if (r < RPB) {
          const int j  = (r >= NJ) ? r - NJ : r;
          const int fb = r - j;
          const int k0 = rps[j], k1 = rps[j + 1];
          float4 o = make_float4(0.f, 0.f, 0.f, 0.f);
          for (int k = k0; k < k1; ++k) {
            const int col = jjs[k];
            const ushort4 wk = *(const ushort4*)&wkb[k * NC + c0];
            const int hr = fb + col;
            const int nb = ((col == j ? 0 : 128) + c0) * 2;
            const ushort4 hv = *(const ushort4*)((const char*)hsm + hr * 512 +
                                                 (nb ^ ((hr & 7) << 4)));
            o.x += bf2f(wk.x) * bf2f(hv.x);
            o.y += bf2f(wk.y) * bf2f(hv.y);
            o.z += bf2f(wk.z) * bf2f(hv.z);
            o.w += bf2f(wk.w) * bf2f(hv.w);
          }
          *(float4*)(op + r * NC + c0) = o;   // fire-and-forget (never drained)
        }
      }
    }

    if (more) {                   // vmcnt wait happens HERE via register dep
      STAGE(buf ^ 1);
      buf ^= 1;
    }
  }
#undef LOADX
#undef STW
#undef STAGE
}

// ---------------------------------------------------------------------------
extern "C" void kernel_launch(void* const* d_in, const int* in_sizes, int n_in,
                              void* d_out, int out_size, void* d_ws, size_t ws_size,
                              hipStream_t stream) {
  const float* x  = (const float*)d_in[0];  // [B,T,J,F]
  const float* W  = (const float*)d_in[1];  // [2,F,C]
  const float* e  = (const float*)d_in[2];  // [C,NNZ]
  const int*   ii = (const int*)d_in[3];    // [NNZ]
  const int*   jj = (const int*)d_in[4];    // [NNZ]
  float* out = (float*)d_out;

  bf16x8* Wpack = (bf16x8*)d_ws;
  ushort* wnb   = (ushort*)((char*)d_ws + WS_WNB);
  int*    rpp   = (int*)((char*)d_ws + WS_RP);

  prep_pack_kernel<<<17, 256, 0, stream>>>((const float*)d_in[1], e, ii,
                                           Wpack, wnb, rpp);

  const int frames = in_sizes[0] / (NJ * FD);   // 15552
  const int ntiles = frames / FR;               // 7776
  fused_kernel<<<768, 256, 0, stream>>>(x, Wpack, wnb, rpp, jj, out, ntiles);
}